// Round 1
// baseline (1623.328 us; speedup 1.0000x reference)
//
#include <hip/hip_runtime.h>

#define NU 500000
#define NI 200000
#define NE 2000000
#define HD 32
#define DF 256
#define OC 96   // output row stride = 3*H

__device__ __forceinline__ float lrelu(float v){ return v >= 0.f ? v : 0.01f*v; }

__global__ void k_zero_i32(int* __restrict__ p, int n){
  int i = blockIdx.x*blockDim.x + threadIdx.x;
  if (i < n) p[i] = 0;
}

// final_user[:,0:32] = user_emb[user_ids]; zero cols 32:96 (layer-1/2 accumulators)
__global__ void k_init_user(const int* __restrict__ ids, const float* __restrict__ emb,
                            float* __restrict__ outu){
  int i = blockIdx.x*blockDim.x + threadIdx.x;
  if (i >= NU) return;
  int uid = ids[i];
  const float4* s = (const float4*)(emb + (size_t)uid*HD);
  float4* d = (float4*)(outu + (size_t)i*OC);
  #pragma unroll
  for (int q = 0; q < 8; ++q) d[q] = s[q];
  float4 z = make_float4(0.f,0.f,0.f,0.f);
  #pragma unroll
  for (int q = 8; q < 24; ++q) d[q] = z;
}

// final_item[:,0:32] = item_emb[product_ids] + feat @ W^T + b; zero cols 32:96
__global__ void k_init_item(const int* __restrict__ ids, const float* __restrict__ emb,
                            const float* __restrict__ feat, const float* __restrict__ W,
                            const float* __restrict__ b, float* __restrict__ outi){
  int i = blockIdx.x*blockDim.x + threadIdx.x;
  if (i >= NI) return;
  int pid = ids[i];
  float acc[HD];
  const float4* ev = (const float4*)(emb + (size_t)pid*HD);
  #pragma unroll
  for (int q = 0; q < 8; ++q) {
    float4 e4 = ev[q];
    acc[q*4+0] = e4.x + b[q*4+0];
    acc[q*4+1] = e4.y + b[q*4+1];
    acc[q*4+2] = e4.z + b[q*4+2];
    acc[q*4+3] = e4.w + b[q*4+3];
  }
  const float* f = feat + (size_t)i*DF;
  for (int k0 = 0; k0 < DF; k0 += 8) {
    float4 a0 = *(const float4*)(f + k0);
    float4 a1 = *(const float4*)(f + k0 + 4);
    float fv[8] = {a0.x,a0.y,a0.z,a0.w,a1.x,a1.y,a1.z,a1.w};
    #pragma unroll
    for (int kk = 0; kk < 8; ++kk) {
      #pragma unroll
      for (int h = 0; h < HD; ++h) acc[h] += fv[kk]*W[h*DF + k0 + kk];  // W uniform -> s_load
    }
  }
  float* dst = outi + (size_t)i*OC;
  #pragma unroll
  for (int q = 0; q < 8; ++q)
    ((float4*)dst)[q] = make_float4(acc[q*4+0], acc[q*4+1], acc[q*4+2], acc[q*4+3]);
  float4 z = make_float4(0.f,0.f,0.f,0.f);
  #pragma unroll
  for (int q = 8; q < 24; ++q) ((float4*)dst)[q] = z;
}

// degrees from edge_rates: cnt_u = hist(src users), cnt_p = hist(dst items)
__global__ void k_deg(const int* __restrict__ esrc, const int* __restrict__ edst,
                      int* __restrict__ cnt_u, int* __restrict__ cnt_p){
  int e = blockIdx.x*blockDim.x + threadIdx.x;
  if (e >= NE) return;
  atomicAdd(cnt_u + esrc[e], 1);
  atomicAdd(cnt_p + edst[e], 1);
}

// 32 lanes per edge: acc[dst, aoff+h] += src[s, soff+h]; both arrays stride OC
__global__ void k_agg(const float* __restrict__ srcbase, int soff,
                      const int* __restrict__ esrc, const int* __restrict__ edst,
                      float* __restrict__ accbase, int aoff){
  int t = blockIdx.x*blockDim.x + threadIdx.x;
  int e = t >> 5;
  if (e >= NE) return;
  int h = t & 31;
  int s = esrc[e], d = edst[e];
  atomicAdd(accbase + (size_t)d*OC + aoff + h, srcbase[(size_t)s*OC + soff + h]);
}

// in-place: row[outoff:outoff+32] = lrelu( (row[accoff:..]/max(cnt,1)) @ Wl^T + bl + row[xoff:..] @ Wr^T )
__global__ void k_fin(float* __restrict__ base, int n, int accoff, int xoff, int outoff,
                      const int* __restrict__ cnt, const float* __restrict__ Wl,
                      const float* __restrict__ bl, const float* __restrict__ Wr){
  int i = blockIdx.x*blockDim.x + threadIdx.x;
  if (i >= n) return;
  float* row = base + (size_t)i*OC;
  int c = cnt[i]; if (c < 1) c = 1;
  float inv = 1.f/(float)c;
  float m[HD], x[HD];
  #pragma unroll
  for (int q = 0; q < 8; ++q) {
    float4 a = *(const float4*)(row + accoff + q*4);
    m[q*4+0]=a.x*inv; m[q*4+1]=a.y*inv; m[q*4+2]=a.z*inv; m[q*4+3]=a.w*inv;
    float4 xx = *(const float4*)(row + xoff + q*4);
    x[q*4+0]=xx.x; x[q*4+1]=xx.y; x[q*4+2]=xx.z; x[q*4+3]=xx.w;
  }
  float y[HD];
  #pragma unroll
  for (int h = 0; h < HD; ++h) {
    float s = bl[h];
    #pragma unroll
    for (int j = 0; j < HD; ++j) s += m[j]*Wl[h*HD+j];   // uniform -> s_load
    #pragma unroll
    for (int j = 0; j < HD; ++j) s += x[j]*Wr[h*HD+j];
    y[h] = lrelu(s);
  }
  #pragma unroll
  for (int q = 0; q < 8; ++q)
    *((float4*)(row + outoff + q*4)) = make_float4(y[q*4+0],y[q*4+1],y[q*4+2],y[q*4+3]);
}

extern "C" void kernel_launch(void* const* d_in, const int* in_sizes, int n_in,
                              void* d_out, int out_size, void* d_ws, size_t ws_size,
                              hipStream_t stream) {
  const int*   user_ids = (const int*)d_in[0];
  const int*   prod_ids = (const int*)d_in[1];
  const float* feat     = (const float*)d_in[2];
  const int*   er       = (const int*)d_in[3];   // [2, NE]: row0 = user(src), row1 = item(dst)
  const int*   erb      = (const int*)d_in[4];   // [2, NE]: row0 = item(src), row1 = user(dst)
  const float* uemb     = (const float*)d_in[5];
  const float* iemb     = (const float*)d_in[6];
  const float* fW       = (const float*)d_in[7];
  const float* fb       = (const float*)d_in[8];
  const float* Wl_up1 = (const float*)d_in[9];
  const float* bl_up1 = (const float*)d_in[10];
  const float* Wr_up1 = (const float*)d_in[11];
  const float* Wl_pu1 = (const float*)d_in[12];
  const float* bl_pu1 = (const float*)d_in[13];
  const float* Wr_pu1 = (const float*)d_in[14];
  const float* Wl_up2 = (const float*)d_in[15];
  const float* bl_up2 = (const float*)d_in[16];
  const float* Wr_up2 = (const float*)d_in[17];
  const float* Wl_pu2 = (const float*)d_in[18];
  const float* bl_pu2 = (const float*)d_in[19];
  const float* Wr_pu2 = (const float*)d_in[20];

  float* outu = (float*)d_out;
  float* outi = outu + (size_t)NU*OC;
  int* cnt_u = (int*)d_ws;        // NU ints
  int* cnt_p = cnt_u + NU;        // NI ints

  const int* er_src  = er;        // users
  const int* er_dst  = er + NE;   // items
  const int* erb_src = erb;       // items
  const int* erb_dst = erb + NE;  // users

  const int B = 256;
  k_zero_i32<<<(NU+NI+B-1)/B, B, 0, stream>>>(cnt_u, NU+NI);
  k_init_user<<<(NU+B-1)/B, B, 0, stream>>>(user_ids, uemb, outu);
  k_init_item<<<(NI+B-1)/B, B, 0, stream>>>(prod_ids, iemb, feat, fW, fb, outi);
  k_deg<<<(NE+B-1)/B, B, 0, stream>>>(er_src, er_dst, cnt_u, cnt_p);

  const int agrid = (NE*32 + B - 1)/B;
  // layer 1
  k_agg<<<agrid, B, 0, stream>>>(outu, 0, er_src, er_dst, outi, 32);    // users -> item sums
  k_agg<<<agrid, B, 0, stream>>>(outi, 0, erb_src, erb_dst, outu, 32);  // items -> user sums
  k_fin<<<(NI+B-1)/B, B, 0, stream>>>(outi, NI, 32, 0, 32, cnt_p, Wl_up1, bl_up1, Wr_up1);
  k_fin<<<(NU+B-1)/B, B, 0, stream>>>(outu, NU, 32, 0, 32, cnt_u, Wl_pu1, bl_pu1, Wr_pu1);
  // layer 2
  k_agg<<<agrid, B, 0, stream>>>(outu, 32, er_src, er_dst, outi, 64);   // u1 -> item sums
  k_agg<<<agrid, B, 0, stream>>>(outi, 32, erb_src, erb_dst, outu, 64); // p1 -> user sums
  k_fin<<<(NI+B-1)/B, B, 0, stream>>>(outi, NI, 64, 32, 64, cnt_p, Wl_up2, bl_up2, Wr_up2);
  k_fin<<<(NU+B-1)/B, B, 0, stream>>>(outu, NU, 64, 32, 64, cnt_u, Wl_pu2, bl_pu2, Wr_pu2);
}